// Round 4
// baseline (265.496 us; speedup 1.0000x reference)
//
#include <hip/hip_runtime.h>
#include <hip/hip_bf16.h>
#include <cstdint>

// Problem constants
#define NTOK 8192
#define DIN  1024
#define DOUT 1024
#define NEXP 8

typedef __attribute__((ext_vector_type(8)))  __bf16 bf16x8;
typedef __attribute__((ext_vector_type(4)))  float  f32x4;
typedef __attribute__((ext_vector_type(16))) float  f32x16;

__device__ __forceinline__ unsigned short f2bf(float f) {
    unsigned int u = __builtin_bit_cast(unsigned int, f);
    u += 0x7FFFu + ((u >> 16) & 1u);   // round-to-nearest-even
    return (unsigned short)(u >> 16);
}

__device__ __forceinline__ void cp16(const void* gsrc, void* ldst) {
    __builtin_amdgcn_global_load_lds(
        (const __attribute__((address_space(1))) void*)gsrc,
        (__attribute__((address_space(3))) void*)ldst,
        16, 0, 0);
}

#define BAR() asm volatile("s_barrier" ::: "memory")

// ---------------------------------------------------------------------------
// Prep kernel (unchanged):
//   blocks [0, 2048):     We [e][k][o] fp32 -> WebT [e][o][k] bf16
//   blocks [2048, 2304):  gate softmax(x@Wg+bg) + x -> bf16
// ---------------------------------------------------------------------------
__global__ __launch_bounds__(256) void prep_kernel(
    const float* __restrict__ x, const float* __restrict__ We,
    const float* __restrict__ Wg, const float* __restrict__ bg,
    unsigned short* __restrict__ xb, unsigned short* __restrict__ wt,
    float* __restrict__ g)
{
    __shared__ float smem[12416];

    int t = threadIdx.x;

    if (blockIdx.x < 2048) {
        unsigned short* tile = (unsigned short*)smem;   // [64][72]
        int b = blockIdx.x;
        int e  = b >> 8;
        int kt = (b >> 4) & 15;
        int ot = b & 15;

        const float* src = We + ((size_t)e << 20) + (size_t)(kt * 64) * DOUT + ot * 64;
        unsigned short* dst = wt + ((size_t)e << 20) + (size_t)(ot * 64) * DIN + kt * 64;

        int kl = t >> 2;
        int og = (t & 3) * 16;
#pragma unroll
        for (int c = 0; c < 4; ++c) {
            int o = og + c * 4;
            float4 v = *(const float4*)&src[(size_t)kl * DOUT + o];
            ushort4 u;
            u.x = f2bf(v.x); u.y = f2bf(v.y); u.z = f2bf(v.z); u.w = f2bf(v.w);
            *(ushort4*)&tile[kl * 72 + o] = u;
        }
        __syncthreads();
        int ol = t >> 2;
        int kg = (t & 3) * 16;
        unsigned short tmp[16];
#pragma unroll
        for (int i = 0; i < 16; ++i) tmp[i] = tile[(kg + i) * 72 + ol];
        *(uint4*)&dst[(size_t)ol * DIN + kg]     = *(uint4*)&tmp[0];
        *(uint4*)&dst[(size_t)ol * DIN + kg + 8] = *(uint4*)&tmp[8];
    } else {
        float* WgL = smem;          // [8][1024] transposed Wg
        float* xL  = smem + 8192;   // [32][132] x chunk
        int n0 = (blockIdx.x - 2048) * 32;

#pragma unroll
        for (int q = 0; q < 8; ++q) {
            int fidx = q * 256 + t;
            int k  = fidx >> 1;
            int eh = (fidx & 1) * 4;
            float4 v = *(const float4*)&Wg[(size_t)k * 8 + eh];
            WgL[(eh + 0) * 1024 + k] = v.x;
            WgL[(eh + 1) * 1024 + k] = v.y;
            WgL[(eh + 2) * 1024 + k] = v.z;
            WgL[(eh + 3) * 1024 + k] = v.w;
        }

        int tt = t & 31;
        int e  = t >> 5;
        float acc = 0.f;

        for (int c = 0; c < 8; ++c) {
            int kb = c * 128;
#pragma unroll
            for (int q = 0; q < 4; ++q) {
                int fidx = q * 256 + t;
                int row = fidx >> 5;
                int kk  = (fidx & 31) * 4;
                float4 v = *(const float4*)&x[(size_t)(n0 + row) * DIN + kb + kk];
                ushort4 u;
                u.x = f2bf(v.x); u.y = f2bf(v.y); u.z = f2bf(v.z); u.w = f2bf(v.w);
                *(ushort4*)&xb[(size_t)(n0 + row) * DIN + kb + kk] = u;
                *(float4*)&xL[row * 132 + kk] = v;
            }
            __syncthreads();
#pragma unroll
            for (int kk = 0; kk < 128; kk += 4) {
                float4 xv = *(const float4*)&xL[tt * 132 + kk];
                float4 wv = *(const float4*)&WgL[e * 1024 + kb + kk];
                acc += xv.x * wv.x + xv.y * wv.y + xv.z * wv.z + xv.w * wv.w;
            }
            __syncthreads();
        }

        float* lg = xL;
        lg[tt * 8 + e] = acc + bg[e];
        __syncthreads();
        if (t < 32) {
            float l[8];
#pragma unroll
            for (int i = 0; i < 8; ++i) l[i] = lg[t * 8 + i];
            float m = l[0];
#pragma unroll
            for (int i = 1; i < 8; ++i) m = fmaxf(m, l[i]);
            float s = 0.f;
#pragma unroll
            for (int i = 0; i < 8; ++i) { l[i] = __expf(l[i] - m); s += l[i]; }
            float inv = 1.0f / s;
            float4 p0 = make_float4(l[0]*inv, l[1]*inv, l[2]*inv, l[3]*inv);
            float4 p1 = make_float4(l[4]*inv, l[5]*inv, l[6]*inv, l[7]*inv);
            *(float4*)&g[(size_t)(n0 + tt) * 8]     = p0;
            *(float4*)&g[(size_t)(n0 + tt) * 8 + 4] = p1;
        }
    }
}

// ---------------------------------------------------------------------------
// Main MoE GEMM — 32x32x16 MFMA restructure:
//  - same BM=256 x BN=32 x BK=64, dbuf 128KB, byte-identical staging/swizzle
//  - waves 4M x 2EG: wm owns a 64-row slab, eg owns experts {0-3} or {4-7};
//    per wave: 2 Mblocks(32) x 4 experts, acc = 8 x f32x16 = 128 regs
//  - mfma_f32_32x32x16_bf16: 32 KFLOP per pair of b128 operand reads — HALF
//    the LDS bytes/FLOP of 16x16x32, and 8.07 cyc vs 9.7 per 32 KFLOP.
//    Per-CU per K-tile: MFMA 2066 cyc, LDS reads ~1536 cyc (was 2483+2300)
//  - 2 phases/K-tile (ksteps 0-1 / 2-3); next phase's frags are read BEFORE
//    the phase barrier (latency under barrier, m201 placement); A-stage at
//    P0, B-stage at P1, vmcnt(0)+BAR once per tile (B is XCD-L2-hot)
//  - epilogue: gated partials over each wave's 4 experts, cross-wave (eg0 ->
//    eg1) reduction through 32KB of LDS, single extra barrier
//  - fragment layouts: A/B row=lane&31, k=(lane>>5)*8+j (family pattern);
//    C/D col=lane&31, row=(reg&3)+8*(reg>>2)+4*(lane>>5) (m74/m101 verified)
// ---------------------------------------------------------------------------
__global__ __launch_bounds__(512, 2) void moe_gemm_kernel(
    const unsigned short* __restrict__ xb,   // [NTOK][DIN] bf16
    const unsigned short* __restrict__ wt,   // [E][DOUT][DIN] bf16
    const float* __restrict__ g,             // [NTOK][E]
    const float* __restrict__ be,            // [E][DOUT]
    float* __restrict__ out)                 // [NTOK][DOUT]
{
    __shared__ unsigned short lA[2][256 * 64];   // 2 x 32 KB
    __shared__ unsigned short lB[2][256 * 64];   // 2 x 32 KB (8e x 32col)

    int bid = blockIdx.x;                 // 0..1023
    int xcd = bid & 7;
    int wl  = bid >> 3;                   // 0..127
    int bn  = xcd * 4 + (wl & 3);         // 0..31, XCD-local B panels
    int bm  = wl >> 2;                    // 0..31

    int tid  = threadIdx.x;               // 0..511
    int lane = tid & 63;
    int wave = tid >> 6;                  // 0..7
    int wm   = wave >> 1;                 // 0..3 (64-row slab of 256)
    int eg   = wave & 1;                  // 0..1 (expert group)
    int ebase = eg * 4;

    int ln31 = lane & 31;                 // MFMA row/col within 32
    int kg   = lane >> 5;                 // k-group 0..1 (8 elems each)
    int s    = ln31 & 7;                  // swizzle key (rows are 0 mod 32)

    // physical chunk offsets for ksteps 0..3 (chunk = ks*2 + kg, XOR row&7)
    int kpo[4];
#pragma unroll
    for (int ks = 0; ks < 4; ++ks) kpo[ks] = (((ks * 2 + kg) ^ s) << 3);

    int aRow[2], bRow[4];
#pragma unroll
    for (int mb = 0; mb < 2; ++mb) aRow[mb] = (wm * 64 + mb * 32 + ln31) * 64;
#pragma unroll
    for (int el = 0; el < 4; ++el) bRow[el] = ((ebase + el) * 32 + ln31) * 64;

    // staging geometry (byte-identical to R2/R3): thread covers
    // (row = base + tid>>3, phys chunk tid&7); phys holds logical ^ (row&7)
    int srow   = tid >> 3;                            // 0..63
    int schunk = ((tid & 7) ^ (srow & 7)) << 3;
    int wOff   = wave * 512;                          // elems

    const unsigned short* aBase = xb + (size_t)(bm * 256 + srow) * DIN + schunk;
    int eLo  = srow >> 5;                 // 0..1
    int colB = srow & 31;
    const unsigned short* bBase = wt + (size_t)(bn * 32 + colB) * DIN + schunk;

#define STAGE_A(b, tt, H)                                                        \
    {   size_t ko = (size_t)(tt) * 64;                                           \
        cp16(aBase + (size_t)((H) * 128 +  0) * DIN + ko,                        \
             &lA[b][(H) * 8192 + 0 * 4096 + wOff]);                              \
        cp16(aBase + (size_t)((H) * 128 + 64) * DIN + ko,                        \
             &lA[b][(H) * 8192 + 1 * 4096 + wOff]); }
#define STAGE_B(b, tt, H)                                                        \
    {   size_t ko = (size_t)(tt) * 64;                                           \
        cp16(bBase + (((size_t)((H) * 4 + 0 + eLo)) << 20) + ko,                 \
             &lB[b][(H) * 8192 + 0 * 4096 + wOff]);                              \
        cp16(bBase + (((size_t)((H) * 4 + 2 + eLo)) << 20) + ko,                 \
             &lB[b][(H) * 8192 + 1 * 4096 + wOff]); }

    // read the 12 frags (2 ksteps) starting at kstep kb from bufs A/B
    bf16x8 af[2][2], bf[4][2];
#define RD_FRAGS(Ab, Bb, kb)                                                     \
    {                                                                            \
        af[0][0] = *(const bf16x8*)&(Ab)[aRow[0] + kpo[(kb) + 0]];               \
        af[1][0] = *(const bf16x8*)&(Ab)[aRow[1] + kpo[(kb) + 0]];               \
        af[0][1] = *(const bf16x8*)&(Ab)[aRow[0] + kpo[(kb) + 1]];               \
        af[1][1] = *(const bf16x8*)&(Ab)[aRow[1] + kpo[(kb) + 1]];               \
        _Pragma("unroll")                                                        \
        for (int el = 0; el < 4; ++el) {                                         \
            bf[el][0] = *(const bf16x8*)&(Bb)[bRow[el] + kpo[(kb) + 0]];         \
            bf[el][1] = *(const bf16x8*)&(Bb)[bRow[el] + kpo[(kb) + 1]];         \
        }                                                                        \
    }

#define MFMA_PHASE()                                                             \
    {   __builtin_amdgcn_s_setprio(1);                                           \
        _Pragma("unroll")                                                        \
        for (int q = 0; q < 2; ++q)                                              \
            _Pragma("unroll")                                                    \
            for (int el = 0; el < 4; ++el)                                       \
                _Pragma("unroll")                                                \
                for (int mb = 0; mb < 2; ++mb)                                   \
                    acc[el][mb] = __builtin_amdgcn_mfma_f32_32x32x16_bf16(       \
                        af[mb][q], bf[el][q], acc[el][mb], 0, 0, 0);             \
        __builtin_amdgcn_s_setprio(0); }

    // ---- prologue: stage K-tile 0 into buf0 ----
    STAGE_A(0, 0, 0); STAGE_A(0, 0, 1);
    STAGE_B(0, 0, 0); STAGE_B(0, 0, 1);

    f32x16 acc[4][2] = {};   // [expert_local][mblock]

    asm volatile("s_waitcnt vmcnt(0)" ::: "memory");
    BAR();
    RD_FRAGS(lA[0], lB[0], 0);

#pragma unroll 1
    for (int t = 0; t < 16; ++t) {
        int c = t & 1, n = c ^ 1;
        const unsigned short* A = lA[c];
        const unsigned short* B = lB[c];

        // ---- P0: MFMA ksteps 0,1 (frags preloaded); stage A(t+1) ----
        if (t < 15) { STAGE_A(n, t + 1, 0); STAGE_A(n, t + 1, 1); }
        MFMA_PHASE();
        RD_FRAGS(A, B, 2);                 // next phase's frags, before barrier
        BAR();

        // ---- P1: MFMA ksteps 2,3; stage B(t+1); publish tile t+1 ----
        if (t < 15) { STAGE_B(n, t + 1, 0); STAGE_B(n, t + 1, 1); }
        MFMA_PHASE();
        if (t < 15) asm volatile("s_waitcnt vmcnt(0)" ::: "memory");
        BAR();                             // tile t+1 staged & published
        if (t < 15) RD_FRAGS(lA[n], lB[n], 0);   // tile t+1 phase-0 frags
    }

    // ---- epilogue: gated partials + cross-wave (eg) reduction via LDS ----
    int colg = bn * 32 + ln31;
    float bcol[4];
#pragma unroll
    for (int el = 0; el < 4; ++el)
        bcol[el] = be[(size_t)(ebase + el) * DOUT + colg];

    float part[2][16];
#pragma unroll
    for (int mb = 0; mb < 2; ++mb)
#pragma unroll
        for (int r = 0; r < 16; ++r) {
            int rloc = mb * 32 + (r & 3) + 8 * (r >> 2) + 4 * kg;   // 0..63
            int rowg = bm * 256 + wm * 64 + rloc;
            float4 gv = *(const float4*)&g[(size_t)rowg * 8 + ebase];
            part[mb][r] = gv.x * (acc[0][mb][r] + bcol[0])
                        + gv.y * (acc[1][mb][r] + bcol[1])
                        + gv.z * (acc[2][mb][r] + bcol[2])
                        + gv.w * (acc[3][mb][r] + bcol[3]);
        }

    float* red = (float*)lA;   // 32KB scratch (lA[0..] free: last reads fenced)
    if (eg == 0) {
#pragma unroll
        for (int mb = 0; mb < 2; ++mb)
#pragma unroll
            for (int r = 0; r < 16; ++r) {
                int rloc = mb * 32 + (r & 3) + 8 * (r >> 2) + 4 * kg;
                red[wm * 2048 + rloc * 32 + ln31] = part[mb][r];
            }
    }
    __syncthreads();
    if (eg == 1) {
#pragma unroll
        for (int mb = 0; mb < 2; ++mb)
#pragma unroll
            for (int r = 0; r < 16; ++r) {
                int rloc = mb * 32 + (r & 3) + 8 * (r >> 2) + 4 * kg;
                int rowg = bm * 256 + wm * 64 + rloc;
                out[(size_t)rowg * DOUT + colg] =
                    part[mb][r] + red[wm * 2048 + rloc * 32 + ln31];
            }
    }
}

// ---------------------------------------------------------------------------
extern "C" void kernel_launch(void* const* d_in, const int* in_sizes, int n_in,
                              void* d_out, int out_size, void* d_ws, size_t ws_size,
                              hipStream_t stream)
{
    const float* x  = (const float*)d_in[0];   // [8192,1024]
    const float* We = (const float*)d_in[1];   // [8,1024,1024]
    const float* be = (const float*)d_in[2];   // [8,1024]
    const float* Wg = (const float*)d_in[3];   // [1024,8]
    const float* bg = (const float*)d_in[4];   // [8]
    float* out = (float*)d_out;                // [8192,1024]

    // workspace: xb (16.78MB bf16) | WebT (16.78MB bf16) | g (256KB f32)
    unsigned short* xb = (unsigned short*)d_ws;
    unsigned short* wt = xb + (size_t)NTOK * DIN;
    float* g = (float*)(wt + (size_t)NEXP * DOUT * DIN);

    prep_kernel<<<2048 + 256, 256, 0, stream>>>(x, We, Wg, bg, xb, wt, g);
    moe_gemm_kernel<<<(NTOK / 256) * (DOUT / 32), 512, 0, stream>>>(xb, wt, g, be, out);
}